// Round 1
// baseline (477.158 us; speedup 1.0000x reference)
//
#include <hip/hip_runtime.h>
#include <math.h>

#define N 8192
#define FIN 256
#define D 64
#define ALPHA 0.2f
#define BR 64
#define BC 64
#define PR 68   // padded LDS row stride (floats); 68*4 B = 16B-aligned for b128

// ---------------- Kernel 1: h = x @ trans, e1 = h@attn[:64], e2 = h@attn[64:] ----
__global__ __launch_bounds__(256) void k_h_e(
    const float* __restrict__ x, const float* __restrict__ trans,
    const float* __restrict__ attn, float* __restrict__ h,
    float* __restrict__ e1, float* __restrict__ e2)
{
    __shared__ float xs[4 * FIN];
    const int tid = threadIdx.x;
    const int row0 = blockIdx.x * 4;
    // stage 4 rows of x (4*256 floats) coalesced
    ((float4*)xs)[tid] = ((const float4*)(x + (size_t)row0 * FIN))[tid];
    __syncthreads();
    const int w = tid >> 6;      // row within block (one wave per row)
    const int lane = tid & 63;   // output column
    const float* xr = xs + w * FIN;
    float acc = 0.f;
    #pragma unroll 8
    for (int k = 0; k < FIN; ++k)
        acc = fmaf(xr[k], trans[k * D + lane], acc);
    const int gi = row0 + w;
    h[(size_t)gi * D + lane] = acc;
    float p1 = acc * attn[lane];
    float p2 = acc * attn[D + lane];
    #pragma unroll
    for (int m = 32; m >= 1; m >>= 1) {
        p1 += __shfl_xor(p1, m);
        p2 += __shfl_xor(p2, m);
    }
    if (lane == 0) { e1[gi] = p1; e2[gi] = p2; }
}

// ---------------- Kernel 2: fused masked-softmax attention, partial over col split
// block: 256 threads, BR=64 rows, loops over cs columns in BC=64 tiles.
// No row-max needed: scores bounded (|e|~13), p = mask ? exp(s) : 0; out = acc/l.
__global__ __launch_bounds__(256) void k_attn(
    const int* __restrict__ mask, const float* __restrict__ h,
    const float* __restrict__ e1, const float* __restrict__ e2,
    float* __restrict__ acc_part, float* __restrict__ l_part, int cs)
{
    __shared__ __align__(16) float pT[BR * PR];   // [r][j]
    __shared__ __align__(16) float hT[BC * PR];   // [j][c]
    __shared__ float e1s[BR];
    __shared__ float l_lds[BR];

    const int tid = threadIdx.x;
    const int i0 = blockIdx.y * BR;
    const int sp = blockIdx.x;      // column split index
    const int c0 = sp * cs;

    if (tid < BR) { l_lds[tid] = 0.f; e1s[tid] = e1[i0 + tid]; }
    __syncthreads();

    const int rg = tid >> 4;   // 0..15 -> rows 4*rg..4*rg+3
    const int cg = tid & 15;   // 0..15 -> cols 4*cg..4*cg+3
    float acc[4][4];
    #pragma unroll
    for (int a = 0; a < 4; ++a)
        #pragma unroll
        for (int b = 0; b < 4; ++b) acc[a][b] = 0.f;

    for (int jt = 0; jt < cs; jt += BC) {
        const int j0 = c0 + jt;
        // ---- Phase A: scores -> pT[r][j], stage h tile -> hT[j][c], l partials
        #pragma unroll
        for (int t = 0; t < 4; ++t) {
            const int u = tid + 256 * t;
            const int j4 = u & 15;    // float4 group within tile row
            const int r  = u >> 4;    // tile row (also tile j-row for h staging)
            const int4   mv = *(const int4*)(mask + (size_t)(i0 + r) * N + j0 + 4 * j4);
            const float4 ev = *(const float4*)(e2 + j0 + 4 * j4);
            const float  er = e1s[r];
            float s0 = er + ev.x; s0 = s0 > 0.f ? s0 : ALPHA * s0;
            float s1 = er + ev.y; s1 = s1 > 0.f ? s1 : ALPHA * s1;
            float s2 = er + ev.z; s2 = s2 > 0.f ? s2 : ALPHA * s2;
            float s3 = er + ev.w; s3 = s3 > 0.f ? s3 : ALPHA * s3;
            float4 pv;
            pv.x = mv.x ? __expf(s0) : 0.f;
            pv.y = mv.y ? __expf(s1) : 0.f;
            pv.z = mv.z ? __expf(s2) : 0.f;
            pv.w = mv.w ? __expf(s3) : 0.f;
            *(float4*)(pT + r * PR + 4 * j4) = pv;
            // stage h tile row r (reusing same (r, j4) decomposition: c = 4*j4)
            const float4 hv = *(const float4*)(h + (size_t)(j0 + r) * D + 4 * j4);
            *(float4*)(hT + r * PR + 4 * j4) = hv;
            // l partial: 16 lanes (same r) cover the 64 j's of this row
            float ps = pv.x + pv.y + pv.z + pv.w;
            ps += __shfl_xor(ps, 1);
            ps += __shfl_xor(ps, 2);
            ps += __shfl_xor(ps, 4);
            ps += __shfl_xor(ps, 8);
            if ((tid & 15) == 0) l_lds[r] += ps;
        }
        __syncthreads();
        // ---- Phase B: acc[4][4] += P[4 rows][64 j] * H[64 j][4 cols]
        #pragma unroll 4
        for (int jj = 0; jj < 16; ++jj) {
            const float4 hv0 = *(const float4*)(hT + (4 * jj + 0) * PR + 4 * cg);
            const float4 hv1 = *(const float4*)(hT + (4 * jj + 1) * PR + 4 * cg);
            const float4 hv2 = *(const float4*)(hT + (4 * jj + 2) * PR + 4 * cg);
            const float4 hv3 = *(const float4*)(hT + (4 * jj + 3) * PR + 4 * cg);
            #pragma unroll
            for (int a = 0; a < 4; ++a) {
                const float4 pv = *(const float4*)(pT + (4 * rg + a) * PR + 4 * jj);
                acc[a][0] = fmaf(pv.x, hv0.x, acc[a][0]);
                acc[a][1] = fmaf(pv.x, hv0.y, acc[a][1]);
                acc[a][2] = fmaf(pv.x, hv0.z, acc[a][2]);
                acc[a][3] = fmaf(pv.x, hv0.w, acc[a][3]);
                acc[a][0] = fmaf(pv.y, hv1.x, acc[a][0]);
                acc[a][1] = fmaf(pv.y, hv1.y, acc[a][1]);
                acc[a][2] = fmaf(pv.y, hv1.z, acc[a][2]);
                acc[a][3] = fmaf(pv.y, hv1.w, acc[a][3]);
                acc[a][0] = fmaf(pv.z, hv2.x, acc[a][0]);
                acc[a][1] = fmaf(pv.z, hv2.y, acc[a][1]);
                acc[a][2] = fmaf(pv.z, hv2.z, acc[a][2]);
                acc[a][3] = fmaf(pv.z, hv2.w, acc[a][3]);
                acc[a][0] = fmaf(pv.w, hv3.x, acc[a][0]);
                acc[a][1] = fmaf(pv.w, hv3.y, acc[a][1]);
                acc[a][2] = fmaf(pv.w, hv3.z, acc[a][2]);
                acc[a][3] = fmaf(pv.w, hv3.w, acc[a][3]);
            }
        }
        __syncthreads();
    }
    // ---- write partials
    #pragma unroll
    for (int a = 0; a < 4; ++a) {
        float4 st = make_float4(acc[a][0], acc[a][1], acc[a][2], acc[a][3]);
        *(float4*)(acc_part + ((size_t)sp * N + i0 + 4 * rg + a) * D + 4 * cg) = st;
    }
    if (tid < BR) l_part[(size_t)sp * N + i0 + tid] = l_lds[tid];
}

// ---------------- Kernel 3: combine splits, divide by l --------------------------
__global__ __launch_bounds__(256) void k_reduce(
    const float* __restrict__ acc_part, const float* __restrict__ l_part,
    float* __restrict__ out, int nsplit)
{
    const int idx = blockIdx.x * 256 + threadIdx.x;
    const int row = idx >> 6;
    float sum = 0.f, l = 0.f;
    for (int s = 0; s < nsplit; ++s) {
        sum += acc_part[(size_t)s * N * D + idx];
        l   += l_part[(size_t)s * N + row];
    }
    out[idx] = sum / l;
}

extern "C" void kernel_launch(void* const* d_in, const int* in_sizes, int n_in,
                              void* d_out, int out_size, void* d_ws, size_t ws_size,
                              hipStream_t stream) {
    const float* x     = (const float*)d_in[0];
    const int*   mask  = (const int*)d_in[1];
    const float* trans = (const float*)d_in[2];
    const float* attn  = (const float*)d_in[3];
    float* out = (float*)d_out;

    char* ws = (char*)d_ws;
    float* h  = (float*)ws;                                   // N*D floats (2 MB)
    float* e1 = (float*)(ws + (size_t)N * D * sizeof(float));
    float* e2 = e1 + N;
    float* l_part = e2 + N;

    // pick the largest column split whose partials fit in ws
    const size_t base = (size_t)N * D * sizeof(float) + 2 * (size_t)N * sizeof(float);
    int nsplit = 1;
    const int cands[4] = {8, 4, 2, 1};
    for (int ci = 0; ci < 4; ++ci) {
        int s = cands[ci];
        size_t need = base + (size_t)s * N * sizeof(float)
                    + (size_t)s * N * D * sizeof(float);
        if (need <= ws_size) { nsplit = s; break; }
    }
    float* acc_part = l_part + (size_t)nsplit * N;

    k_h_e<<<N / 4, 256, 0, stream>>>(x, trans, attn, h, e1, e2);
    dim3 g2(nsplit, N / BR);
    k_attn<<<g2, 256, 0, stream>>>(mask, h, e1, e2, acc_part, l_part, N / nsplit);
    k_reduce<<<(N * D) / 256, 256, 0, stream>>>(acc_part, l_part, out, nsplit);
}

// Round 2
// 444.455 us; speedup vs baseline: 1.0736x; 1.0736x over previous
//
#include <hip/hip_runtime.h>
#include <hip/hip_bf16.h>
#include <math.h>

#define N 8192
#define FIN 256
#define D 64
#define ALPHA 0.2f

typedef __attribute__((ext_vector_type(8))) short bf16x8;
typedef __attribute__((ext_vector_type(4))) float f32x4;

// ---------------- Kernel 1: h = x@trans (fp32), e1/e2 (fp32), hT bf16 transposed
// block 256 thr = 32 rows. Thread (g = t>>4, cg = t&15) computes rows {2g,2g+1},
// cols {4cg..4cg+3}: 8 FMA per ds_read_b64 -> VALU-bound, ~4 us.
__global__ __launch_bounds__(256) void k_h_e(
    const float* __restrict__ x, const float* __restrict__ trans,
    const float* __restrict__ attn,
    __hip_bfloat16* __restrict__ hT, float* __restrict__ e1, float* __restrict__ e2)
{
    __shared__ float xT[FIN * 34];            // [k][row], stride 34 (even -> b64 ok)
    __shared__ __hip_bfloat16 hl[32 * D];     // [row][d] for transposed write
    const int t = threadIdx.x;
    const int r0 = blockIdx.x * 32;

    // stage x -> xT (transposed). fidx = c4*32 + r keeps LDS writes conflict-free.
    #pragma unroll
    for (int v = 0; v < 8; ++v) {
        int fidx = v * 256 + t;
        int r = fidx & 31, c4 = fidx >> 5;
        float4 xv = *(const float4*)(x + (size_t)(r0 + r) * FIN + c4 * 4);
        xT[(c4 * 4 + 0) * 34 + r] = xv.x;
        xT[(c4 * 4 + 1) * 34 + r] = xv.y;
        xT[(c4 * 4 + 2) * 34 + r] = xv.z;
        xT[(c4 * 4 + 3) * 34 + r] = xv.w;
    }
    __syncthreads();

    const int cg = t & 15, g = t >> 4;
    const int d0 = cg * 4;
    const float4 a1 = *(const float4*)(attn + d0);
    const float4 a2 = *(const float4*)(attn + D + d0);

    float acc0[4] = {0.f, 0.f, 0.f, 0.f};
    float acc1[4] = {0.f, 0.f, 0.f, 0.f};
    #pragma unroll 4
    for (int k = 0; k < FIN; ++k) {
        const float2 xp = *(const float2*)(xT + k * 34 + 2 * g);
        const float4 tv = *(const float4*)(trans + k * D + d0);
        acc0[0] = fmaf(xp.x, tv.x, acc0[0]);
        acc0[1] = fmaf(xp.x, tv.y, acc0[1]);
        acc0[2] = fmaf(xp.x, tv.z, acc0[2]);
        acc0[3] = fmaf(xp.x, tv.w, acc0[3]);
        acc1[0] = fmaf(xp.y, tv.x, acc1[0]);
        acc1[1] = fmaf(xp.y, tv.y, acc1[1]);
        acc1[2] = fmaf(xp.y, tv.z, acc1[2]);
        acc1[3] = fmaf(xp.y, tv.w, acc1[3]);
    }
    const int row0 = r0 + 2 * g, row1 = row0 + 1;

    // e1/e2 = h . attn halves, reduced over the 16 cg lanes (fp32 throughout)
    float p1a = acc0[0]*a1.x + acc0[1]*a1.y + acc0[2]*a1.z + acc0[3]*a1.w;
    float p1b = acc1[0]*a1.x + acc1[1]*a1.y + acc1[2]*a1.z + acc1[3]*a1.w;
    float p2a = acc0[0]*a2.x + acc0[1]*a2.y + acc0[2]*a2.z + acc0[3]*a2.w;
    float p2b = acc1[0]*a2.x + acc1[1]*a2.y + acc1[2]*a2.z + acc1[3]*a2.w;
    #pragma unroll
    for (int m君 = 1; m君 <= 8; m君 <<= 1) {
        p1a += __shfl_xor(p1a, m君);
        p1b += __shfl_xor(p1b, m君);
        p2a += __shfl_xor(p2a, m君);
        p2b += __shfl_xor(p2b, m君);
    }
    if (cg == 0) {
        e1[row0] = p1a; e1[row1] = p1b;
        e2[row0] = p2a; e2[row1] = p2b;
    }

    // h -> LDS (bf16), then transposed coalesced write to hT[d][row]
    __hip_bfloat162* hp0 = (__hip_bfloat162*)(hl + (2 * g) * D + d0);
    __hip_bfloat162* hp1 = (__hip_bfloat162*)(hl + (2 * g + 1) * D + d0);
    hp0[0] = __float22bfloat162_rn(make_float2(acc0[0], acc0[1]));
    hp0[1] = __float22bfloat162_rn(make_float2(acc0[2], acc0[3]));
    hp1[0] = __float22bfloat162_rn(make_float2(acc1[0], acc1[1]));
    hp1[1] = __float22bfloat162_rn(make_float2(acc1[2], acc1[3]));
    __syncthreads();
    {
        const int d = t >> 2, rs = (t & 3) * 8;
        union { bf16x8 v; __hip_bfloat16 h[8]; } o;
        #pragma unroll
        for (int i = 0; i < 8; ++i) o.h[i] = hl[(rs + i) * D + d];
        *(bf16x8*)(hT + (size_t)d * N + r0 + rs) = o.v;
    }
}

// ---------------- Kernel 2: fused masked softmax-attention via MFMA ------------
// No LDS, no barriers. Wave owns 16 rows x all 64 d. A-frag (P) built in-register:
// lane l computes P[i0 + (l&15)][jb..jb+7], jb = j + (l>>4)*8 -- exactly the
// mfma_f32_16x16x32_bf16 A layout. B-frag = one b128 from hT[d][j] (L2-resident).
__global__ __launch_bounds__(256) void k_attn(
    const int* __restrict__ mask, const __hip_bfloat16* __restrict__ hT,
    const float* __restrict__ e1, const float* __restrict__ e2,
    float* __restrict__ acc_part, float* __restrict__ l_part, int cs)
{
    const int t = threadIdx.x;
    const int lane = t & 63, wave = t >> 6;
    const int i0 = (blockIdx.y * 4 + wave) * 16;
    const int sp = blockIdx.x;
    const int c0 = sp * cs;
    const int m = lane & 15, quad = lane >> 4;
    const int row = i0 + m;
    const float er = e1[row];
    const size_t mrow = (size_t)row * N;

    f32x4 acc0 = {0.f, 0.f, 0.f, 0.f};
    f32x4 acc1 = {0.f, 0.f, 0.f, 0.f};
    f32x4 acc2 = {0.f, 0.f, 0.f, 0.f};
    f32x4 acc3 = {0.f, 0.f, 0.f, 0.f};
    float lsum = 0.f;

    const __hip_bfloat16* hb0 = hT + (size_t)(m     ) * N;
    const __hip_bfloat16* hb1 = hT + (size_t)(m + 16) * N;
    const __hip_bfloat16* hb2 = hT + (size_t)(m + 32) * N;
    const __hip_bfloat16* hb3 = hT + (size_t)(m + 48) * N;

    for (int j = c0; j < c0 + cs; j += 32) {
        const int jb = j + quad * 8;
        const int4   m0 = *(const int4*)(mask + mrow + jb);
        const int4   m1 = *(const int4*)(mask + mrow + jb + 4);
        const float4 ea = *(const float4*)(e2 + jb);
        const float4 eb = *(const float4*)(e2 + jb + 4);
        const bf16x8 b0 = *(const bf16x8*)(hb0 + jb);
        const bf16x8 b1 = *(const bf16x8*)(hb1 + jb);
        const bf16x8 b2 = *(const bf16x8*)(hb2 + jb);
        const bf16x8 b3 = *(const bf16x8*)(hb3 + jb);

        float s0 = er + ea.x; s0 = s0 > 0.f ? s0 : ALPHA * s0;
        float s1 = er + ea.y; s1 = s1 > 0.f ? s1 : ALPHA * s1;
        float s2 = er + ea.z; s2 = s2 > 0.f ? s2 : ALPHA * s2;
        float s3 = er + ea.w; s3 = s3 > 0.f ? s3 : ALPHA * s3;
        float s4 = er + eb.x; s4 = s4 > 0.f ? s4 : ALPHA * s4;
        float s5 = er + eb.y; s5 = s5 > 0.f ? s5 : ALPHA * s5;
        float s6 = er + eb.z; s6 = s6 > 0.f ? s6 : ALPHA * s6;
        float s7 = er + eb.w; s7 = s7 > 0.f ? s7 : ALPHA * s7;
        const float p0 = m0.x ? __expf(s0) : 0.f;
        const float p1 = m0.y ? __expf(s1) : 0.f;
        const float p2 = m0.z ? __expf(s2) : 0.f;
        const float p3 = m0.w ? __expf(s3) : 0.f;
        const float p4 = m1.x ? __expf(s4) : 0.f;
        const float p5 = m1.y ? __expf(s5) : 0.f;
        const float p6 = m1.z ? __expf(s6) : 0.f;
        const float p7 = m1.w ? __expf(s7) : 0.f;

        union { bf16x8 v; __hip_bfloat162 h2[4]; } af;
        af.h2[0] = __float22bfloat162_rn(make_float2(p0, p1));
        af.h2[1] = __float22bfloat162_rn(make_float2(p2, p3));
        af.h2[2] = __float22bfloat162_rn(make_float2(p4, p5));
        af.h2[3] = __float22bfloat162_rn(make_float2(p6, p7));

        lsum += ((p0 + p1) + (p2 + p3)) + ((p4 + p5) + (p6 + p7));

        acc0 = __builtin_amdgcn_mfma_f32_16x16x32_bf16(af.v, b0, acc0, 0, 0, 0);
        acc1 = __builtin_amdgcn_mfma_f32_16x16x32_bf16(af.v, b1, acc1, 0, 0, 0);
        acc2 = __builtin_amdgcn_mfma_f32_16x16x32_bf16(af.v, b2, acc2, 0, 0, 0);
        acc3 = __builtin_amdgcn_mfma_f32_16x16x32_bf16(af.v, b3, acc3, 0, 0, 0);
    }

    // row m's columns live in lanes m, m+16, m+32, m+48
    lsum += __shfl_xor(lsum, 16);
    lsum += __shfl_xor(lsum, 32);
    if (quad == 0) l_part[(size_t)sp * N + row] = lsum;

    // C/D layout: col = lane&15 (+16*nt), row = quad*4 + reg
    #pragma unroll
    for (int reg = 0; reg < 4; ++reg) {
        const size_t rbase = ((size_t)sp * N + i0 + quad * 4 + reg) * D;
        acc_part[rbase + m     ] = acc0[reg];
        acc_part[rbase + m + 16] = acc1[reg];
        acc_part[rbase + m + 32] = acc2[reg];
        acc_part[rbase + m + 48] = acc3[reg];
    }
}

// ---------------- Kernel 3: combine splits, divide by l ------------------------
__global__ __launch_bounds__(256) void k_reduce(
    const float* __restrict__ acc_part, const float* __restrict__ l_part,
    float* __restrict__ out, int nsplit)
{
    const int idx = blockIdx.x * 256 + threadIdx.x;
    const int row = idx >> 6;
    float sum = 0.f, l = 0.f;
    for (int s = 0; s < nsplit; ++s) {
        sum += acc_part[(size_t)s * N * D + idx];
        l   += l_part[(size_t)s * N + row];
    }
    out[idx] = sum / l;
}

extern "C" void kernel_launch(void* const* d_in, const int* in_sizes, int n_in,
                              void* d_out, int out_size, void* d_ws, size_t ws_size,
                              hipStream_t stream) {
    const float* x     = (const float*)d_in[0];
    const int*   mask  = (const int*)d_in[1];
    const float* trans = (const float*)d_in[2];
    const float* attn  = (const float*)d_in[3];
    float* out = (float*)d_out;

    char* ws = (char*)d_ws;
    __hip_bfloat16* hT = (__hip_bfloat16*)ws;                 // D*N bf16 = 1 MB
    float* e1 = (float*)(ws + (size_t)D * N * sizeof(__hip_bfloat16));
    float* e2 = e1 + N;
    float* l_part = e2 + N;

    const size_t base = (size_t)D * N * sizeof(__hip_bfloat16)
                      + 2 * (size_t)N * sizeof(float);
    int nsplit = 1;
    const int cands[5] = {16, 8, 4, 2, 1};
    for (int ci = 0; ci < 5; ++ci) {
        int s = cands[ci];
        size_t need = base + (size_t)s * N * sizeof(float)
                    + (size_t)s * N * D * sizeof(float);
        if (need <= ws_size) { nsplit = s; break; }
    }
    float* acc_part = l_part + (size_t)nsplit * N;

    k_h_e<<<N / 32, 256, 0, stream>>>(x, trans, attn, hT, e1, e2);
    dim3 g2(nsplit, N / 64);
    k_attn<<<g2, 256, 0, stream>>>(mask, hT, e1, e2, acc_part, l_part, N / nsplit);
    k_reduce<<<(N * D) / 256, 256, 0, stream>>>(acc_part, l_part, out, nsplit);
}

// Round 3
// 437.631 us; speedup vs baseline: 1.0903x; 1.0156x over previous
//
#include <hip/hip_runtime.h>
#include <hip/hip_bf16.h>
#include <math.h>

#define N 8192
#define FIN 256
#define D 64
#define ALPHA 0.2f

typedef __attribute__((ext_vector_type(8))) short bf16x8;
typedef __attribute__((ext_vector_type(4))) float f32x4;

// ---------------- Kernel 1: h = x@trans (fp32), e1/e2 (fp32), hT bf16 transposed
// 1024 blocks x 8 rows, 4 waves/block, 2 rows/wave, lane = output col d.
// 2 FMA per trans dword (L1-resident); x rows broadcast from LDS.
__global__ __launch_bounds__(256) void k_h_e(
    const float* __restrict__ x, const float* __restrict__ trans,
    const float* __restrict__ attn,
    __hip_bfloat16* __restrict__ hT, float* __restrict__ e1, float* __restrict__ e2)
{
    __shared__ float xs[8 * FIN];            // [row][k]
    __shared__ __hip_bfloat16 hl[8 * D];     // [row][d]
    const int t = threadIdx.x;
    const int r0 = blockIdx.x * 8;

    #pragma unroll
    for (int v = 0; v < 2; ++v) {
        int idx = t + 256 * v;               // 0..511 float4 slots
        ((float4*)xs)[idx] = ((const float4*)(x + (size_t)r0 * FIN))[idx];
    }
    __syncthreads();

    const int lane = t & 63, w = t >> 6;
    const float* xa = xs + (2 * w) * FIN;
    const float* xb = xs + (2 * w + 1) * FIN;
    float acca = 0.f, accb = 0.f;
    #pragma unroll 8
    for (int k = 0; k < FIN; ++k) {
        const float tv = trans[k * D + lane];
        acca = fmaf(xa[k], tv, acca);
        accb = fmaf(xb[k], tv, accb);
    }
    const int ra = r0 + 2 * w, rb = ra + 1;

    // e1/e2: fp32 dot with attn halves, full-wave reduction
    const float a1 = attn[lane], a2 = attn[D + lane];
    float p1a = acca * a1, p2a = acca * a2;
    float p1b = accb * a1, p2b = accb * a2;
    #pragma unroll
    for (int mm = 1; mm <= 32; mm <<= 1) {
        p1a += __shfl_xor(p1a, mm);
        p2a += __shfl_xor(p2a, mm);
        p1b += __shfl_xor(p1b, mm);
        p2b += __shfl_xor(p2b, mm);
    }
    if (lane == 0) { e1[ra] = p1a; e2[ra] = p2a; e1[rb] = p1b; e2[rb] = p2b; }

    // hT[d][row] (bf16) via small LDS transpose
    hl[(2 * w) * D + lane]     = __float2bfloat16(acca);
    hl[(2 * w + 1) * D + lane] = __float2bfloat16(accb);
    __syncthreads();
    if (t < D) {
        union { bf16x8 v; __hip_bfloat16 h[8]; } o;
        #pragma unroll
        for (int r = 0; r < 8; ++r) o.h[r] = hl[r * D + t];
        *(bf16x8*)(hT + (size_t)t * N + r0) = o.v;
    }
}

// ---------------- Kernel 2: fused masked softmax-attention via MFMA ------------
// No LDS, no barriers. Wave owns 16 rows x all 64 d. A-frag (P) built in-register:
// lane l computes P[i0 + (l&15)][jb..jb+7], jb = j + (l>>4)*8 -- exactly the
// mfma_f32_16x16x32_bf16 A layout. B-frag = one b128 from hT[d][j] (L2-resident).
__global__ __launch_bounds__(256) void k_attn(
    const int* __restrict__ mask, const __hip_bfloat16* __restrict__ hT,
    const float* __restrict__ e1, const float* __restrict__ e2,
    float* __restrict__ acc_part, float* __restrict__ l_part, int cs)
{
    const int t = threadIdx.x;
    const int lane = t & 63, wave = t >> 6;
    const int i0 = (blockIdx.y * 4 + wave) * 16;
    const int sp = blockIdx.x;
    const int c0 = sp * cs;
    const int m = lane & 15, quad = lane >> 4;
    const int row = i0 + m;
    const float er = e1[row];
    const size_t mrow = (size_t)row * N;

    f32x4 acc0 = {0.f, 0.f, 0.f, 0.f};
    f32x4 acc1 = {0.f, 0.f, 0.f, 0.f};
    f32x4 acc2 = {0.f, 0.f, 0.f, 0.f};
    f32x4 acc3 = {0.f, 0.f, 0.f, 0.f};
    float lsum = 0.f;

    const __hip_bfloat16* hb0 = hT + (size_t)(m     ) * N;
    const __hip_bfloat16* hb1 = hT + (size_t)(m + 16) * N;
    const __hip_bfloat16* hb2 = hT + (size_t)(m + 32) * N;
    const __hip_bfloat16* hb3 = hT + (size_t)(m + 48) * N;

    #pragma unroll 2
    for (int j = c0; j < c0 + cs; j += 32) {
        const int jb = j + quad * 8;
        const int4   m0 = *(const int4*)(mask + mrow + jb);
        const int4   m1 = *(const int4*)(mask + mrow + jb + 4);
        const float4 ea = *(const float4*)(e2 + jb);
        const float4 eb = *(const float4*)(e2 + jb + 4);
        const bf16x8 b0 = *(const bf16x8*)(hb0 + jb);
        const bf16x8 b1 = *(const bf16x8*)(hb1 + jb);
        const bf16x8 b2 = *(const bf16x8*)(hb2 + jb);
        const bf16x8 b3 = *(const bf16x8*)(hb3 + jb);

        float s0 = er + ea.x; s0 = s0 > 0.f ? s0 : ALPHA * s0;
        float s1 = er + ea.y; s1 = s1 > 0.f ? s1 : ALPHA * s1;
        float s2 = er + ea.z; s2 = s2 > 0.f ? s2 : ALPHA * s2;
        float s3 = er + ea.w; s3 = s3 > 0.f ? s3 : ALPHA * s3;
        float s4 = er + eb.x; s4 = s4 > 0.f ? s4 : ALPHA * s4;
        float s5 = er + eb.y; s5 = s5 > 0.f ? s5 : ALPHA * s5;
        float s6 = er + eb.z; s6 = s6 > 0.f ? s6 : ALPHA * s6;
        float s7 = er + eb.w; s7 = s7 > 0.f ? s7 : ALPHA * s7;
        const float p0 = m0.x ? __expf(s0) : 0.f;
        const float p1 = m0.y ? __expf(s1) : 0.f;
        const float p2 = m0.z ? __expf(s2) : 0.f;
        const float p3 = m0.w ? __expf(s3) : 0.f;
        const float p4 = m1.x ? __expf(s4) : 0.f;
        const float p5 = m1.y ? __expf(s5) : 0.f;
        const float p6 = m1.z ? __expf(s6) : 0.f;
        const float p7 = m1.w ? __expf(s7) : 0.f;

        union { bf16x8 v; __hip_bfloat162 h2[4]; } af;
        af.h2[0] = __float22bfloat162_rn(make_float2(p0, p1));
        af.h2[1] = __float22bfloat162_rn(make_float2(p2, p3));
        af.h2[2] = __float22bfloat162_rn(make_float2(p4, p5));
        af.h2[3] = __float22bfloat162_rn(make_float2(p6, p7));

        lsum += ((p0 + p1) + (p2 + p3)) + ((p4 + p5) + (p6 + p7));

        acc0 = __builtin_amdgcn_mfma_f32_16x16x32_bf16(af.v, b0, acc0, 0, 0, 0);
        acc1 = __builtin_amdgcn_mfma_f32_16x16x32_bf16(af.v, b1, acc1, 0, 0, 0);
        acc2 = __builtin_amdgcn_mfma_f32_16x16x32_bf16(af.v, b2, acc2, 0, 0, 0);
        acc3 = __builtin_amdgcn_mfma_f32_16x16x32_bf16(af.v, b3, acc3, 0, 0, 0);
    }

    // row m's columns live in lanes m, m+16, m+32, m+48
    lsum += __shfl_xor(lsum, 16);
    lsum += __shfl_xor(lsum, 32);
    if (quad == 0) l_part[(size_t)sp * N + row] = lsum;

    // C/D layout: col = lane&15 (+16 per acc frag), row = quad*4 + reg
    #pragma unroll
    for (int reg = 0; reg < 4; ++reg) {
        const size_t rbase = ((size_t)sp * N + i0 + quad * 4 + reg) * D;
        acc_part[rbase + m     ] = acc0[reg];
        acc_part[rbase + m + 16] = acc1[reg];
        acc_part[rbase + m + 32] = acc2[reg];
        acc_part[rbase + m + 48] = acc3[reg];
    }
}

// ---------------- Kernel 3: combine splits, divide by l ------------------------
__global__ __launch_bounds__(256) void k_reduce(
    const float* __restrict__ acc_part, const float* __restrict__ l_part,
    float* __restrict__ out, int nsplit)
{
    const int idx = blockIdx.x * 256 + threadIdx.x;
    const int row = idx >> 6;
    float sum = 0.f, l = 0.f;
    for (int s = 0; s < nsplit; ++s) {
        sum += acc_part[(size_t)s * N * D + idx];
        l   += l_part[(size_t)s * N + row];
    }
    out[idx] = sum / l;
}

extern "C" void kernel_launch(void* const* d_in, const int* in_sizes, int n_in,
                              void* d_out, int out_size, void* d_ws, size_t ws_size,
                              hipStream_t stream) {
    const float* x     = (const float*)d_in[0];
    const int*   mask  = (const int*)d_in[1];
    const float* trans = (const float*)d_in[2];
    const float* attn  = (const float*)d_in[3];
    float* out = (float*)d_out;

    char* ws = (char*)d_ws;
    __hip_bfloat16* hT = (__hip_bfloat16*)ws;                 // D*N bf16 = 1 MB
    float* e1 = (float*)(ws + (size_t)D * N * sizeof(__hip_bfloat16));
    float* e2 = e1 + N;
    float* l_part = e2 + N;

    const size_t base = (size_t)D * N * sizeof(__hip_bfloat16)
                      + 2 * (size_t)N * sizeof(float);
    int nsplit = 1;
    const int cands[4] = {8, 4, 2, 1};
    for (int ci = 0; ci < 4; ++ci) {
        int s = cands[ci];
        size_t need = base + (size_t)s * N * sizeof(float)
                    + (size_t)s * N * D * sizeof(float);
        if (need <= ws_size) { nsplit = s; break; }
    }
    float* acc_part = l_part + (size_t)nsplit * N;

    k_h_e<<<N / 8, 256, 0, stream>>>(x, trans, attn, hT, e1, e2);
    dim3 g2(nsplit, N / 64);
    k_attn<<<g2, 256, 0, stream>>>(mask, hT, e1, e2, acc_part, l_part, N / nsplit);
    k_reduce<<<(N * D) / 256, 256, 0, stream>>>(acc_part, l_part, out, nsplit);
}